// Round 3
// baseline (13935.324 us; speedup 1.0000x reference)
//
#include <hip/hip_runtime.h>
#include <hip/hip_cooperative_groups.h>
#include <math.h>

namespace cg = cooperative_groups;

#define B_  64
#define N_  512
#define H_  1024
#define NH_ 8
#define HD_ 128
#define S_  24

struct Params {
  const float *enc, *h0, *c0, *x0;
  const float *W_ih, *b_ih, *W_hh, *b_hh;
  const float *Wqkv, *bqkv, *Wout, *bout, *Wqt, *bqt;
  float *P, *hbuf, *cbuf, *hq, *qbuf, *ctx, *xbuf, *Kc, *Vc;
  float *logits, *idx;
};

// ---------------------------------------------------------------------------
// GEMM tile: 64 rows (batch) x 128 cols, split-K slice KS.
// 512 threads: tn=tid&31 (4 cols), tm=tid>>5 (4 rows), 16 FMA per k.
// W must be pre-offset to the tile's first row. Pdst = P + sp*64*N + nb*128.
// ---------------------------------------------------------------------------
__device__ __forceinline__ void gemm_tile(
    const float* __restrict__ A, const float* __restrict__ W,
    int ld, int koff, int KS, float* __restrict__ Pdst, int N,
    float* As /*16x68*/, float* Bs /*16x132*/)
{
  const int tid = threadIdx.x;
  const int tn = tid & 31, tm = tid >> 5;
  const int lr = tid >> 2, lc = (tid & 3) * 4;
  float acc[4][4];
#pragma unroll
  for (int i = 0; i < 4; ++i)
#pragma unroll
    for (int j = 0; j < 4; ++j) acc[i][j] = 0.f;

  const float* Wrow = W + (size_t)lr * ld + koff + lc;     // lr 0..127
  const float* Arow = A + (size_t)lr * ld + koff + lc;     // used if tid<256 (lr 0..63)

  for (int k0 = 0; k0 < KS; k0 += 16) {
    float4 b4 = *(const float4*)(Wrow + k0);
    if (tid < 256) {
      float4 a4 = *(const float4*)(Arow + k0);
      As[(lc + 0) * 68 + lr] = a4.x; As[(lc + 1) * 68 + lr] = a4.y;
      As[(lc + 2) * 68 + lr] = a4.z; As[(lc + 3) * 68 + lr] = a4.w;
    }
    Bs[(lc + 0) * 132 + lr] = b4.x; Bs[(lc + 1) * 132 + lr] = b4.y;
    Bs[(lc + 2) * 132 + lr] = b4.z; Bs[(lc + 3) * 132 + lr] = b4.w;
    __syncthreads();
#pragma unroll
    for (int k = 0; k < 16; ++k) {
      float av[4], bv[4];
      *(float4*)av = *(const float4*)(As + k * 68 + tm * 4);
      *(float4*)bv = *(const float4*)(Bs + k * 132 + tn * 4);
#pragma unroll
      for (int i = 0; i < 4; ++i)
#pragma unroll
        for (int j = 0; j < 4; ++j)
          acc[i][j] = fmaf(av[i], bv[j], acc[i][j]);
    }
    __syncthreads();
  }
#pragma unroll
  for (int i = 0; i < 4; ++i)
    *(float4*)(Pdst + (size_t)(tm * 4 + i) * N + tn * 4) =
        make_float4(acc[i][0], acc[i][1], acc[i][2], acc[i][3]);
}

__device__ __forceinline__ float sigm(float x) { return 1.f / (1.f + expf(-x)); }

__device__ __forceinline__ void ins3(float v, int i,
    float& v0, int& i0, float& v1, int& i1, float& v2, int& i2)
{
  if (v > v0 || (v == v0 && i < i0)) {
    v2 = v1; i2 = i1; v1 = v0; i1 = i0; v0 = v; i0 = i;
  } else if (v > v1 || (v == v1 && i < i1)) {
    v2 = v1; i2 = i1; v1 = v; i1 = i;
  } else if (v > v2 || (v == v2 && i < i2)) {
    v2 = v; i2 = i;
  }
}

// ---------------------------------------------------------------------------
// Persistent cooperative kernel: 256 blocks x 512 threads, all 24 steps.
// ---------------------------------------------------------------------------
__global__ __launch_bounds__(512, 2) void decoder(Params p)
{
  cg::grid_group grid = cg::this_grid();
  __shared__ float smem[3200];
  float* As = smem;            // 16*68
  float* Bs = smem + 1088;     // 16*132

  const int tid = threadIdx.x;
  const int bid = blockIdx.x;
  const int gtid = bid * 512 + tid;

  for (int t = 0; t < S_; ++t) {
    const float* xin   = t ? p.xbuf : p.x0;
    const float* hprev = t ? p.hbuf : p.h0;
    const float* cprev = t ? p.cbuf : p.c0;

    // ---- phase 1: gates = [x|h] @ [W_ih|W_hh]^T -> P[8][64][4096], 256 tasks
    {
      int nb = bid & 31, sp = bid >> 5;
      int ks = sp * 512;
      const float* A; const float* W; int ld, koff;
      if (ks < 3072) { A = xin;   W = p.W_ih; ld = 3072; koff = ks; }
      else           { A = hprev; W = p.W_hh; ld = 1024; koff = ks - 3072; }
      gemm_tile(A, W + (size_t)nb * 128 * ld, ld, koff, 512,
                p.P + (size_t)sp * 64 * 4096 + nb * 128, 4096, As, Bs);
    }
    grid.sync();

    // ---- phase 2: LSTM reduce+pointwise -> hbuf, cbuf
    if (gtid < 65536) {
      int b = gtid >> 10, j = gtid & 1023;
      float gv[4];
#pragma unroll
      for (int c = 0; c < 4; ++c) {
        int n = j + 1024 * c;
        float s = p.b_ih[n] + p.b_hh[n];
#pragma unroll
        for (int sp = 0; sp < 8; ++sp) s += p.P[((size_t)sp * 64 + b) * 4096 + n];
        gv[c] = s;
      }
      float c = sigm(gv[1]) * cprev[gtid] + sigm(gv[0]) * tanhf(gv[2]);
      p.cbuf[gtid] = c;
      p.hbuf[gtid] = sigm(gv[3]) * tanhf(c);
    }
    grid.sync();

    // ---- phase 3: qkv = h @ Wqkv^T -> P[8][64][3072], 192 tasks
    if (bid < 192) {
      int nb = bid % 24, sp = bid / 24;
      gemm_tile(p.hbuf, p.Wqkv + (size_t)nb * 128 * 1024, 1024, sp * 128, 128,
                p.P + (size_t)sp * 64 * 3072 + nb * 128, 3072, As, Bs);
    }
    grid.sync();

    // ---- phase 4: attention (fused qkv reduce). 128 blocks x 4 quarters.
    if (bid < 128) {
      const float scale = 0.08838834764831845f;  // 1/sqrt(128)
      int q4 = tid >> 7, d = tid & 127;
      int task = bid * 4 + q4;                   // 0..511
      int b = task >> 3, h = task & 7;
      const float* Pb = p.P + (size_t)b * 3072 + h * 128 + d;
      float qv = p.bqkv[h * 128 + d];
      float kv = p.bqkv[1024 + h * 128 + d];
      float vv = p.bqkv[2048 + h * 128 + d];
#pragma unroll
      for (int sp = 0; sp < 8; ++sp) {
        const float* pp = Pb + (size_t)sp * 64 * 3072;
        qv += pp[0]; kv += pp[1024]; vv += pp[2048];
      }
      float* Kb = p.Kc + (size_t)(b * NH_ + h) * S_ * HD_;
      float* Vb = p.Vc + (size_t)(b * NH_ + h) * S_ * HD_;
      Kb[t * 128 + d] = kv;
      Vb[t * 128 + d] = vv;
      float* qs = smem + q4 * 128;         // 4*128
      float* sc = smem + 512 + q4 * 24;    // 4*24
      qs[d] = qv;
      __syncthreads();                      // orders global K/V row-t writes too
      int wave = d >> 6, lane = d & 63;
      for (int s = wave; s <= t; s += 2) {
        float pr = qs[lane] * Kb[s * 128 + lane] + qs[lane + 64] * Kb[s * 128 + lane + 64];
#pragma unroll
        for (int off = 32; off > 0; off >>= 1) pr += __shfl_down(pr, off, 64);
        if (lane == 0) sc[s] = pr * scale;
      }
      __syncthreads();
      float m = -3.4e38f;
      for (int s = 0; s <= t; ++s) m = fmaxf(m, sc[s]);
      float den = 0.f;
      for (int s = 0; s <= t; ++s) den += expf(sc[s] - m);
      float acc = 0.f;
      for (int s = 0; s <= t; ++s) acc += expf(sc[s] - m) * Vb[s * 128 + d];
      p.ctx[(size_t)b * 1024 + h * 128 + d] = acc / den;
    }
    grid.sync();

    // ---- phase 5: attn_out = ctx @ Wout^T -> P[16][64][1024], 128 tasks
    if (bid < 128) {
      int nb = bid & 7, sp = bid >> 3;
      gemm_tile(p.ctx, p.Wout + (size_t)nb * 128 * 1024, 1024, sp * 64, 64,
                p.P + (size_t)sp * 64 * 1024 + nb * 128, 1024, As, Bs);
    }
    grid.sync();

    // ---- phase 6: hq = 0.5*(h + attn_out)
    if (gtid < 65536) {
      int b = gtid >> 10, j = gtid & 1023;
      float s = p.bout[j];
#pragma unroll
      for (int sp = 0; sp < 16; ++sp) s += p.P[((size_t)sp * 64 + b) * 1024 + j];
      p.hq[gtid] = 0.5f * (p.hbuf[gtid] + s);
    }
    grid.sync();

    // ---- phase 7: qt = hq @ Wqt^T -> P[16][64][1024], 128 tasks
    if (bid < 128) {
      int nb = bid & 7, sp = bid >> 3;
      gemm_tile(p.hq, p.Wqt + (size_t)nb * 128 * 1024, 1024, sp * 64, 64,
                p.P + (size_t)sp * 64 * 1024 + nb * 128, 1024, As, Bs);
    }
    grid.sync();

    // ---- phase 8: qt reduce -> qbuf
    if (gtid < 65536) {
      int b = gtid >> 10, j = gtid & 1023;
      float s = p.bqt[j];
#pragma unroll
      for (int sp = 0; sp < 16; ++sp) s += p.P[((size_t)sp * 64 + b) * 1024 + j];
      p.qbuf[gtid] = s;
    }
    grid.sync();

    // ---- phase 9: logits[b,n] = dot(query[b], enc[b,n]). 512 tasks, 2/block.
    float* lo = p.logits + (size_t)t * B_ * N_;
#pragma unroll
    for (int ti = 0; ti < 2; ++ti) {
      int task = bid * 2 + ti;
      int b = task >> 3, ng = task & 7;      // 64 n's per task
      for (int i = tid; i < 1024; i += 512) smem[i] = p.qbuf[(size_t)b * 1024 + i];
      __syncthreads();
      int wave = tid >> 6, lane = tid & 63;
      for (int j = 0; j < 8; ++j) {
        int n = ng * 64 + wave * 8 + j;
        const float* e = p.enc + ((size_t)b * N_ + n) * 1024;
        float pr = 0.f;
#pragma unroll
        for (int i = 0; i < 16; ++i) pr = fmaf(smem[lane + 64 * i], e[lane + 64 * i], pr);
#pragma unroll
        for (int off = 32; off > 0; off >>= 1) pr += __shfl_down(pr, off, 64);
        if (lane == 0) lo[(size_t)b * N_ + n] = pr;
      }
      __syncthreads();
    }
    grid.sync();

    // ---- phase 10: top3 + gather next x. 64 blocks.
    if (bid < 64) {
      int b = bid;
      float* sv = smem;                       // 192 floats
      int*   si = (int*)(smem + 192);         // 192 ints
      int*   topi = (int*)(smem + 384);
      const float* lrow = lo + (size_t)b * N_;
      if (tid < 64) {
        float v0 = -3.4e38f, v1 = -3.4e38f, v2 = -3.4e38f;
        int i0 = 0x7fffffff, i1 = 0x7fffffff, i2 = 0x7fffffff;
        for (int n = tid; n < N_; n += 64) ins3(lrow[n], n, v0, i0, v1, i1, v2, i2);
        sv[tid * 3 + 0] = v0; si[tid * 3 + 0] = i0;
        sv[tid * 3 + 1] = v1; si[tid * 3 + 1] = i1;
        sv[tid * 3 + 2] = v2; si[tid * 3 + 2] = i2;
      }
      __syncthreads();
      if (tid == 0) {
        float w0 = -3.4e38f, w1 = -3.4e38f, w2 = -3.4e38f;
        int j0 = 0x7fffffff, j1 = 0x7fffffff, j2 = 0x7fffffff;
        for (int k = 0; k < 192; ++k) ins3(sv[k], si[k], w0, j0, w1, j1, w2, j2);
        int a = j0, bb = j1, c = j2, tw;
        if (a > bb) { tw = a; a = bb; bb = tw; }
        if (bb > c) { tw = bb; bb = c; c = tw; }
        if (a > bb) { tw = a; a = bb; bb = tw; }
        topi[0] = a; topi[1] = bb; topi[2] = c;
        float* io = p.idx + (size_t)t * B_ * 3 + b * 3;
        io[0] = (float)a; io[1] = (float)bb; io[2] = (float)c;
      }
      __syncthreads();
      for (int r = 0; r < 3; ++r) {
        const float* e = p.enc + ((size_t)b * N_ + topi[r]) * 1024;
        for (int i = tid; i < 1024; i += 512)
          p.xbuf[(size_t)b * 3072 + r * 1024 + i] = e[i];
      }
    }
    grid.sync();
  }
}

// ---------------------------------------------------------------------------
extern "C" void kernel_launch(void* const* d_in, const int* in_sizes, int n_in,
                              void* d_out, int out_size, void* d_ws, size_t ws_size,
                              hipStream_t stream)
{
  (void)in_sizes; (void)n_in; (void)out_size; (void)ws_size;
  Params p;
  p.enc   = (const float*)d_in[0];
  p.h0    = (const float*)d_in[1];
  p.c0    = (const float*)d_in[2];
  p.x0    = (const float*)d_in[4];
  p.W_ih  = (const float*)d_in[6];
  p.b_ih  = (const float*)d_in[7];
  p.W_hh  = (const float*)d_in[8];
  p.b_hh  = (const float*)d_in[9];
  p.Wqkv  = (const float*)d_in[10];
  p.bqkv  = (const float*)d_in[11];
  p.Wout  = (const float*)d_in[12];
  p.bout  = (const float*)d_in[13];
  p.Wqt   = (const float*)d_in[14];
  p.bqt   = (const float*)d_in[15];

  float* ws = (float*)d_ws;
  p.P    = ws;                          // 8*64*4096 = 2.097M floats (phase-shared)
  p.hbuf = p.P + 8 * 64 * 4096;
  p.cbuf = p.hbuf + 64 * 1024;
  p.hq   = p.cbuf + 64 * 1024;
  p.qbuf = p.hq + 64 * 1024;
  p.ctx  = p.qbuf + 64 * 1024;
  p.xbuf = p.ctx + 64 * 1024;           // 64*3072
  p.Kc   = p.xbuf + 64 * 3072;          // 64*8*24*128
  p.Vc   = p.Kc + 64 * NH_ * S_ * HD_;

  p.logits = (float*)d_out;                       // [S,B,N]
  p.idx    = p.logits + (size_t)S_ * B_ * N_;     // [S,B,3] as float

  void* args[] = { &p };
  hipLaunchCooperativeKernel((void*)decoder, dim3(256), dim3(512), args, 0, stream);
}